// Round 7
// baseline (217.830 us; speedup 1.0000x reference)
//
#include <hip/hip_runtime.h>
#include <math.h>

#define BB 8
#define CC 512
#define HWSZ 6400
#define NN 100
#define HR 40
#define WR 40
#define VV 20        // N_CLASSES_FG
#define VO 21        // BG + FG
#define TPX 256      // pixels per tile
#define NT (HWSZ / TPX)      // 25 tiles

typedef unsigned long long u64;

// order-preserving float -> uint32 map (min float == min uint)
__device__ __forceinline__ unsigned mapf(float f) {
    unsigned b = __float_as_uint(f);
    return (b & 0x80000000u) ? ~b : (b | 0x80000000u);
}

// ---------------- K1: normalized prototypes [c][v]; zero all counters -------
__global__ __launch_bounds__(512) void k_protos(const float* __restrict__ refc,
                                                const int* __restrict__ coord,
                                                const int* __restrict__ cls,
                                                float* __restrict__ protosT,
                                                u64* __restrict__ batchMin,
                                                unsigned* __restrict__ tileCntA,
                                                unsigned* __restrict__ tileCntB,
                                                unsigned* __restrict__ batchCnt) {
    const int v = blockIdx.x;        // class
    const int c = threadIdx.x;       // channel
    if (v == 0) {
        if (c < BB * NT) { tileCntA[c] = 0u; tileCntB[c] = 0u; }
        if (c < BB) { batchCnt[c] = 0u; batchMin[c] = ~0ull; }
    }

    float acc = 0.f;
    int cnt = 0;
    for (int n = 0; n < NN; ++n) {
        if (cls[n] == v) {           // uniform across block
            int y = coord[2 * n + 1];
            int x = coord[2 * n + 0];
            acc += refc[((size_t)(n * CC + c) * HR + y) * WR + x];
            ++cnt;
        }
    }
    acc /= fmaxf((float)cnt, 1.0f);

    float ss = acc * acc;
    #pragma unroll
    for (int off = 32; off; off >>= 1) ss += __shfl_xor(ss, off);
    __shared__ float sW[8];
    const int wave = c >> 6, lane = c & 63;
    if (lane == 0) sW[wave] = ss;
    __syncthreads();
    float tot = 0.f;
    #pragma unroll
    for (int w = 0; w < 8; ++w) tot += sW[w];
    float scale = 1.0f / fmaxf(sqrtf(tot), 1e-10f);

    protosT[c * VV + v] = acc * scale;
}

// ---------------- K2: partial prob_C (r5 body) + fused finish/argmin/minvec -
// grid = 8b x 25tiles x 2 channel-halves = 400; block = 256 = 4 waves.
// wave w owns channels [cg*256 + w*64, +64); lane owns float4 @ px 4*lane.
__global__ __launch_bounds__(256) void k_probC(const float* __restrict__ codeC,
                                               const float* __restrict__ codeBG,
                                               const float* __restrict__ protosT,
                                               float* __restrict__ partC,
                                               float* __restrict__ probC,
                                               u64* __restrict__ batchMin,
                                               unsigned* __restrict__ tileCntA,
                                               unsigned* __restrict__ batchCnt,
                                               float* __restrict__ minvecN) {
    __shared__ float red[4 * 11 * TPX];   // 45 KB
    __shared__ u64 sKey[4];
    __shared__ int sLast, sBLast;
    __shared__ unsigned sPix;
    __shared__ float sR[4];

    const int tid  = threadIdx.x;
    const int w    = tid >> 6, lane = tid & 63;
    const int blk  = blockIdx.x;          // b*50 + tile*2 + cg
    const int cg   = blk & 1;
    const int tile = (blk >> 1) % NT;
    const int b    = blk / (2 * NT);
    const int c0   = __builtin_amdgcn_readfirstlane(cg * 256 + w * 64);

    const float* src = codeC + ((size_t)(b * CC + c0)) * HWSZ + tile * TPX + 4 * lane;
    const float* pt  = protosT + (size_t)c0 * VV;   // wave-uniform -> s_load

    float4 d[VV];
    #pragma unroll
    for (int v = 0; v < VV; ++v) d[v] = make_float4(0.f, 0.f, 0.f, 0.f);
    float4 ss = make_float4(0.f, 0.f, 0.f, 0.f);

    #pragma unroll 8
    for (int c = 0; c < 64; ++c) {
        float4 x = *(const float4*)(src + (size_t)c * HWSZ);
        ss.x = fmaf(x.x, x.x, ss.x);
        ss.y = fmaf(x.y, x.y, ss.y);
        ss.z = fmaf(x.z, x.z, ss.z);
        ss.w = fmaf(x.w, x.w, ss.w);
        const float* pr = pt + c * VV;
        #pragma unroll
        for (int v = 0; v < VV; ++v) {
            float p = pr[v];
            d[v].x = fmaf(x.x, p, d[v].x);
            d[v].y = fmaf(x.y, p, d[v].y);
            d[v].z = fmaf(x.z, p, d[v].z);
            d[v].w = fmaf(x.w, p, d[v].w);
        }
    }

    float* dstp = partC + (size_t)blk * (VO * TPX);

    // round A: ss + d0..d9 -> part rows 0..10
    *(float4*)&red[(w * 11 + 0) * TPX + 4 * lane] = ss;
    #pragma unroll
    for (int r = 0; r < 10; ++r)
        *(float4*)&red[(w * 11 + 1 + r) * TPX + 4 * lane] = d[r];
    __syncthreads();
    for (int q = tid; q < 11 * TPX; q += 256) {
        float t = red[q] + red[11 * TPX + q] + red[22 * TPX + q] + red[33 * TPX + q];
        dstp[q] = t;
    }
    __syncthreads();

    // round B: d10..d19 -> part rows 11..20
    #pragma unroll
    for (int r = 0; r < 10; ++r)
        *(float4*)&red[(w * 11 + r) * TPX + 4 * lane] = d[10 + r];
    __syncthreads();
    for (int q = tid; q < 10 * TPX; q += 256) {
        float t = red[q] + red[11 * TPX + q] + red[22 * TPX + q] + red[33 * TPX + q];
        dstp[11 * TPX + q] = t;
    }

    // ---- fused finisher: last of the 2 cg-blocks for this (b,tile) ----
    __threadfence();
    if (tid == 0) {
        unsigned old = atomicAdd(&tileCntA[b * NT + tile], 1u);
        sLast = (old == 1u) ? 1 : 0;
    }
    __syncthreads();
    if (!sLast) return;
    __threadfence();   // acquire partner's partials

    const float* p0 = partC + (size_t)(b * 2 * NT + tile * 2) * (VO * TPX);
    const float* p1 = p0 + VO * TPX;

    float ssT = p0[tid] + p1[tid];
    float scale = 1.0f / fmaxf(sqrtf(ssT), 1e-10f);
    float psum = 0.f;
    float* dst = probC + (size_t)b * VV * HWSZ + tile * TPX;
    #pragma unroll
    for (int v = 0; v < VV; ++v) {
        float dv = p0[(1 + v) * TPX + tid] + p1[(1 + v) * TPX + tid];
        float pv = dv * scale;
        dst[(size_t)v * HWSZ + tid] = pv;
        psum += pv;
    }

    u64 key = ((u64)mapf(psum) << 32) | (unsigned)(tile * TPX + tid);
    #pragma unroll
    for (int off = 32; off; off >>= 1) {
        u64 o = __shfl_xor(key, off);
        if (o < key) key = o;
    }
    if (lane == 0) sKey[w] = key;
    __syncthreads();
    if (tid == 0) {
        u64 kk = sKey[0];
        kk = sKey[1] < kk ? sKey[1] : kk;
        kk = sKey[2] < kk ? sKey[2] : kk;
        kk = sKey[3] < kk ? sKey[3] : kk;
        atomicMin(&batchMin[b], kk);
        __threadfence();
        unsigned old = atomicAdd(&batchCnt[b], 1u);
        sBLast = (old == NT - 1) ? 1 : 0;
    }
    __syncthreads();

    // ---- last tile-finisher of this batch: normalized min_vec ----
    if (!sBLast) return;
    if (tid == 0) {
        __threadfence();
        u64 kk = atomicMin(&batchMin[b], ~0ull);   // identity RMW = coherent read
        sPix = (unsigned)(kk & 0xFFFFFFFFull);
    }
    __syncthreads();
    const int pix = (int)sPix;
    float x0 = codeBG[((size_t)(b * CC + tid)) * HWSZ + pix];
    float x1 = codeBG[((size_t)(b * CC + 256 + tid)) * HWSZ + pix];
    float s2 = fmaf(x0, x0, x1 * x1);
    #pragma unroll
    for (int off = 32; off; off >>= 1) s2 += __shfl_xor(s2, off);
    if (lane == 0) sR[w] = s2;
    __syncthreads();
    float totq = sR[0] + sR[1] + sR[2] + sR[3];
    float sc = 1.0f / fmaxf(sqrtf(totq), 1e-10f);
    minvecN[b * CC + tid] = x0 * sc;
    minvecN[b * CC + 256 + tid] = x1 * sc;
}

// ---------------- K3: partial prob_BG (r5 body) + fused softmax/output ------
__global__ __launch_bounds__(256) void k_bg(const float* __restrict__ codeBG,
                                            const float* __restrict__ minvecN,
                                            const float* __restrict__ probC,
                                            float* __restrict__ partBG,
                                            unsigned* __restrict__ tileCntB,
                                            float* __restrict__ out) {
    __shared__ float red[4 * 2 * TPX];   // 8 KB
    __shared__ int sLast;

    const int tid  = threadIdx.x;
    const int w    = tid >> 6, lane = tid & 63;
    const int blk  = blockIdx.x;
    const int cg   = blk & 1;
    const int tile = (blk >> 1) % NT;
    const int b    = blk / (2 * NT);
    const int c0   = __builtin_amdgcn_readfirstlane(cg * 256 + w * 64);

    const float* src = codeBG + ((size_t)(b * CC + c0)) * HWSZ + tile * TPX + 4 * lane;
    const float* mv  = minvecN + b * CC + c0;   // wave-uniform -> s_load

    float4 ss = make_float4(0.f, 0.f, 0.f, 0.f);
    float4 dg = make_float4(0.f, 0.f, 0.f, 0.f);

    #pragma unroll 8
    for (int c = 0; c < 64; ++c) {
        float4 x = *(const float4*)(src + (size_t)c * HWSZ);
        float m = mv[c];
        ss.x = fmaf(x.x, x.x, ss.x);
        ss.y = fmaf(x.y, x.y, ss.y);
        ss.z = fmaf(x.z, x.z, ss.z);
        ss.w = fmaf(x.w, x.w, ss.w);
        dg.x = fmaf(x.x, m, dg.x);
        dg.y = fmaf(x.y, m, dg.y);
        dg.z = fmaf(x.z, m, dg.z);
        dg.w = fmaf(x.w, m, dg.w);
    }

    *(float4*)&red[(w * 2 + 0) * TPX + 4 * lane] = ss;
    *(float4*)&red[(w * 2 + 1) * TPX + 4 * lane] = dg;
    __syncthreads();

    float* dstp = partBG + (size_t)blk * (2 * TPX);
    for (int q = tid; q < 2 * TPX; q += 256) {
        float t = red[q] + red[2 * TPX + q] + red[4 * TPX + q] + red[6 * TPX + q];
        dstp[q] = t;
    }

    // ---- fused finisher: last of the 2 cg-blocks does softmax+output ----
    __threadfence();
    if (tid == 0) {
        unsigned old = atomicAdd(&tileCntB[b * NT + tile], 1u);
        sLast = (old == 1u) ? 1 : 0;
    }
    __syncthreads();
    if (!sLast) return;
    __threadfence();   // acquire partner's partials

    const float* q0 = partBG + (size_t)(b * 2 * NT + tile * 2) * (2 * TPX);
    const float* q1 = q0 + 2 * TPX;

    float ssT = q0[tid] + q1[tid];
    float dgT = q0[TPX + tid] + q1[TPX + tid];
    float pbg = dgT * (1.0f / fmaxf(sqrtf(ssT), 1e-10f));

    float pv[VO];
    pv[0] = pbg;
    const float* pc = probC + (size_t)b * VV * HWSZ + tile * TPX + tid;
    #pragma unroll
    for (int v = 0; v < VV; ++v) pv[v + 1] = pc[(size_t)v * HWSZ];

    float m = pv[0];
    #pragma unroll
    for (int i = 1; i < VO; ++i) m = fmaxf(m, pv[i]);
    float se = 0.f;
    #pragma unroll
    for (int i = 0; i < VO; ++i) { pv[i] = __expf(pv[i] - m); se += pv[i]; }
    float inv = 1.0f / se;

    float* dstq = out + (size_t)b * VO * HWSZ + tile * TPX + tid;
    #pragma unroll
    for (int i = 0; i < VO; ++i) dstq[(size_t)i * HWSZ] = pv[i] * inv;
}

extern "C" void kernel_launch(void* const* d_in, const int* in_sizes, int n_in,
                              void* d_out, int out_size, void* d_ws, size_t ws_size,
                              hipStream_t stream) {
    const float* codeC  = (const float*)d_in[0];
    const float* codeBG = (const float*)d_in[1];
    const float* refc   = (const float*)d_in[2];
    // d_in[3] (ref_code_bg) unused by the reference
    const int* coord = (const int*)d_in[4];
    const int* cls   = (const int*)d_in[5];
    float* out = (float*)d_out;

    char* ws = (char*)d_ws;
    float*    protosT  = (float*)   (ws);              // 40,960 B  [c][v]
    float*    probC    = (float*)   (ws + 40960);      // 4,096,000 B
    float*    minvecN  = (float*)   (ws + 4136960);    // 16,384 B
    u64*      batchMin = (u64*)     (ws + 4153344);    // 64 B
    unsigned* tileCntA = (unsigned*)(ws + 4153408);    // 800 B
    unsigned* tileCntB = (unsigned*)(ws + 4154208);    // 800 B
    unsigned* batchCnt = (unsigned*)(ws + 4155008);    // 32 B
    float*    partC    = (float*)   (ws + 4160000);    // 400*21*256*4 = 8,601,600 B
    float*    partBG   = (float*)   (ws + 12761600);   // 400*2*256*4 = 819,200 B

    k_protos<<<dim3(VV),          dim3(512), 0, stream>>>(refc, coord, cls, protosT,
                                                          batchMin, tileCntA, tileCntB, batchCnt);
    k_probC <<<dim3(BB * NT * 2), dim3(256), 0, stream>>>(codeC, codeBG, protosT, partC, probC,
                                                          batchMin, tileCntA, batchCnt, minvecN);
    k_bg    <<<dim3(BB * NT * 2), dim3(256), 0, stream>>>(codeBG, minvecN, probC, partBG,
                                                          tileCntB, out);
}

// Round 8
// 116.725 us; speedup vs baseline: 1.8662x; 1.8662x over previous
//
#include <hip/hip_runtime.h>
#include <math.h>

#define BB 8
#define CC 512
#define HWSZ 6400
#define NN 100
#define HR 40
#define WR 40
#define VV 20        // N_CLASSES_FG
#define VO 21        // BG + FG
#define TPX 256      // pixels per tile
#define NT (HWSZ / TPX)      // 25 tiles

typedef unsigned long long u64;

// order-preserving float -> uint32 map (min float == min uint)
__device__ __forceinline__ unsigned mapf(float f) {
    unsigned b = __float_as_uint(f);
    return (b & 0x80000000u) ? ~b : (b | 0x80000000u);
}

// ---------------- K1: normalized prototypes, transposed [c][v] --------------
// If-converted gather: all 100 loads issue unconditionally (MLP), predicated add.
__global__ __launch_bounds__(512) void k_protos(const float* __restrict__ refc,
                                                const int* __restrict__ coord,
                                                const int* __restrict__ cls,
                                                float* __restrict__ protosT,
                                                u64* __restrict__ batchMin,
                                                unsigned* __restrict__ batchCnt) {
    const int v = blockIdx.x;        // class
    const int c = threadIdx.x;       // channel
    if (v == 0 && c < BB) { batchMin[c] = ~0ull; batchCnt[c] = 0u; }

    float acc = 0.f;
    int cnt = 0;
    #pragma unroll 10
    for (int n = 0; n < NN; ++n) {
        int cm = cls[n];                  // uniform scalar load (cached)
        int y = coord[2 * n + 1];
        int x = coord[2 * n + 0];
        float val = refc[((size_t)(n * CC + c) * HR + y) * WR + x];  // unconditional
        bool take = (cm == v);
        acc += take ? val : 0.f;
        cnt += take ? 1 : 0;
    }
    acc /= fmaxf((float)cnt, 1.0f);

    float ss = acc * acc;
    #pragma unroll
    for (int off = 32; off; off >>= 1) ss += __shfl_xor(ss, off);
    __shared__ float sW[8];
    const int wave = c >> 6, lane = c & 63;
    if (lane == 0) sW[wave] = ss;
    __syncthreads();
    float tot = 0.f;
    #pragma unroll
    for (int w = 0; w < 8; ++w) tot += sW[w];
    float scale = 1.0f / fmaxf(sqrtf(tot), 1e-10f);

    protosT[c * VV + v] = acc * scale;   // transposed layout for scalar loads
}

// ---------------- K2: partial prob_C sums, float4 streaming (r5 body) -------
// grid = 8b x 25tiles x 2 channel-halves = 400; block = 256 = 4 waves.
// wave w owns channels [cg*256 + w*64, +64); lane owns float4 @ px 4*lane.
// Writes RAW partial sums partC[blk][21][256]  (row0 = ss, rows 1..20 = d).
__global__ __launch_bounds__(256) void k_probC_part(const float* __restrict__ codeC,
                                                    const float* __restrict__ protosT,
                                                    float* __restrict__ partC) {
    __shared__ float red[4 * 11 * TPX];   // 45 KB

    const int tid  = threadIdx.x;
    const int w    = tid >> 6, lane = tid & 63;
    const int blk  = blockIdx.x;          // b*50 + tile*2 + cg
    const int cg   = blk & 1;
    const int tile = (blk >> 1) % NT;
    const int b    = blk / (2 * NT);
    const int c0   = __builtin_amdgcn_readfirstlane(cg * 256 + w * 64);

    const float* src = codeC + ((size_t)(b * CC + c0)) * HWSZ + tile * TPX + 4 * lane;
    const float* pt  = protosT + (size_t)c0 * VV;   // wave-uniform -> s_load

    float4 d[VV];
    #pragma unroll
    for (int v = 0; v < VV; ++v) d[v] = make_float4(0.f, 0.f, 0.f, 0.f);
    float4 ss = make_float4(0.f, 0.f, 0.f, 0.f);

    #pragma unroll 8
    for (int c = 0; c < 64; ++c) {
        float4 x = *(const float4*)(src + (size_t)c * HWSZ);
        ss.x = fmaf(x.x, x.x, ss.x);
        ss.y = fmaf(x.y, x.y, ss.y);
        ss.z = fmaf(x.z, x.z, ss.z);
        ss.w = fmaf(x.w, x.w, ss.w);
        const float* pr = pt + c * VV;
        #pragma unroll
        for (int v = 0; v < VV; ++v) {
            float p = pr[v];
            d[v].x = fmaf(x.x, p, d[v].x);
            d[v].y = fmaf(x.y, p, d[v].y);
            d[v].z = fmaf(x.z, p, d[v].z);
            d[v].w = fmaf(x.w, p, d[v].w);
        }
    }

    float* dstp = partC + (size_t)blk * (VO * TPX);

    // round A: ss + d0..d9 -> part rows 0..10
    *(float4*)&red[(w * 11 + 0) * TPX + 4 * lane] = ss;
    #pragma unroll
    for (int r = 0; r < 10; ++r)
        *(float4*)&red[(w * 11 + 1 + r) * TPX + 4 * lane] = d[r];
    __syncthreads();
    for (int q = tid; q < 11 * TPX; q += 256) {
        float t = red[q] + red[11 * TPX + q] + red[22 * TPX + q] + red[33 * TPX + q];
        dstp[q] = t;
    }
    __syncthreads();

    // round B: d10..d19 -> part rows 11..20
    #pragma unroll
    for (int r = 0; r < 10; ++r)
        *(float4*)&red[(w * 11 + r) * TPX + 4 * lane] = d[10 + r];
    __syncthreads();
    for (int q = tid; q < 10 * TPX; q += 256) {
        float t = red[q] + red[11 * TPX + q] + red[22 * TPX + q] + red[33 * TPX + q];
        dstp[11 * TPX + q] = t;
    }
}

// ---------------- K2b: combine halves -> probC + psum + argmin + minvec -----
// grid = 8b x 25tiles = 200; block = 256 (thread = pixel).
// Last finisher per batch also computes the normalized min_vec (done-counter).
__global__ __launch_bounds__(256) void k_finishC(const float* __restrict__ partC,
                                                 const float* __restrict__ codeBG,
                                                 float* __restrict__ probC,
                                                 u64* __restrict__ batchMin,
                                                 unsigned* __restrict__ batchCnt,
                                                 float* __restrict__ minvecN) {
    __shared__ u64 sKey[4];
    __shared__ int sBLast;
    __shared__ unsigned sPix;
    __shared__ float sR[4];

    const int tid  = threadIdx.x;               // px
    const int lane = tid & 63, w = tid >> 6;
    const int tile = blockIdx.x % NT;
    const int b    = blockIdx.x / NT;

    const float* p0 = partC + ((size_t)(b * 2 * NT + tile * 2)) * (VO * TPX);
    const float* p1 = p0 + VO * TPX;

    float ssT = p0[tid] + p1[tid];
    float scale = 1.0f / fmaxf(sqrtf(ssT), 1e-10f);

    float psum = 0.f;
    float* dst = probC + (size_t)b * VV * HWSZ + tile * TPX;
    #pragma unroll
    for (int v = 0; v < VV; ++v) {
        float dv = p0[(1 + v) * TPX + tid] + p1[(1 + v) * TPX + tid];
        float pv = dv * scale;
        dst[(size_t)v * HWSZ + tid] = pv;
        psum += pv;
    }

    u64 key = ((u64)mapf(psum) << 32) | (unsigned)(tile * TPX + tid);
    #pragma unroll
    for (int off = 32; off; off >>= 1) {
        u64 o = __shfl_xor(key, off);
        if (o < key) key = o;
    }
    if (lane == 0) sKey[w] = key;
    __syncthreads();
    if (tid == 0) {
        u64 kk = sKey[0];
        kk = sKey[1] < kk ? sKey[1] : kk;
        kk = sKey[2] < kk ? sKey[2] : kk;
        kk = sKey[3] < kk ? sKey[3] : kk;
        atomicMin(&batchMin[b], kk);
        __threadfence();
        unsigned old = atomicAdd(&batchCnt[b], 1u);
        sBLast = (old == NT - 1) ? 1 : 0;
    }
    __syncthreads();

    // last finisher of this batch: normalized min_vec
    if (!sBLast) return;
    if (tid == 0) {
        __threadfence();
        u64 kk = atomicMin(&batchMin[b], ~0ull);   // identity RMW = coherent read
        sPix = (unsigned)(kk & 0xFFFFFFFFull);
    }
    __syncthreads();
    const int pix = (int)sPix;
    float x0 = codeBG[((size_t)(b * CC + tid)) * HWSZ + pix];
    float x1 = codeBG[((size_t)(b * CC + 256 + tid)) * HWSZ + pix];
    float s2 = fmaf(x0, x0, x1 * x1);
    #pragma unroll
    for (int off = 32; off; off >>= 1) s2 += __shfl_xor(s2, off);
    if (lane == 0) sR[w] = s2;
    __syncthreads();
    float totq = sR[0] + sR[1] + sR[2] + sR[3];
    float sc = 1.0f / fmaxf(sqrtf(totq), 1e-10f);
    minvecN[b * CC + tid] = x0 * sc;
    minvecN[b * CC + 256 + tid] = x1 * sc;
}

// ---------------- K4: partial prob_BG sums, float4 streaming (r5 body) ------
// Writes partBG[blk][2][256]  (ss row, dg row).
__global__ __launch_bounds__(256) void k_bg_part(const float* __restrict__ codeBG,
                                                 const float* __restrict__ minvecN,
                                                 float* __restrict__ partBG) {
    __shared__ float red[4 * 2 * TPX];   // 8 KB

    const int tid  = threadIdx.x;
    const int w    = tid >> 6, lane = tid & 63;
    const int blk  = blockIdx.x;
    const int cg   = blk & 1;
    const int tile = (blk >> 1) % NT;
    const int b    = blk / (2 * NT);
    const int c0   = __builtin_amdgcn_readfirstlane(cg * 256 + w * 64);

    const float* src = codeBG + ((size_t)(b * CC + c0)) * HWSZ + tile * TPX + 4 * lane;
    const float* mv  = minvecN + b * CC + c0;   // wave-uniform -> s_load

    float4 ss = make_float4(0.f, 0.f, 0.f, 0.f);
    float4 dg = make_float4(0.f, 0.f, 0.f, 0.f);

    #pragma unroll 8
    for (int c = 0; c < 64; ++c) {
        float4 x = *(const float4*)(src + (size_t)c * HWSZ);
        float m = mv[c];
        ss.x = fmaf(x.x, x.x, ss.x);
        ss.y = fmaf(x.y, x.y, ss.y);
        ss.z = fmaf(x.z, x.z, ss.z);
        ss.w = fmaf(x.w, x.w, ss.w);
        dg.x = fmaf(x.x, m, dg.x);
        dg.y = fmaf(x.y, m, dg.y);
        dg.z = fmaf(x.z, m, dg.z);
        dg.w = fmaf(x.w, m, dg.w);
    }

    *(float4*)&red[(w * 2 + 0) * TPX + 4 * lane] = ss;
    *(float4*)&red[(w * 2 + 1) * TPX + 4 * lane] = dg;
    __syncthreads();

    float* dstp = partBG + (size_t)blk * (2 * TPX);
    for (int q = tid; q < 2 * TPX; q += 256) {
        float t = red[q] + red[2 * TPX + q] + red[4 * TPX + q] + red[6 * TPX + q];
        dstp[q] = t;
    }
}

// ---------------- K4b: combine halves -> prob_BG + softmax + out ------------
__global__ __launch_bounds__(256) void k_finishBG(const float* __restrict__ partBG,
                                                  const float* __restrict__ probC,
                                                  float* __restrict__ out) {
    const int tid  = threadIdx.x;               // px
    const int tile = blockIdx.x % NT;
    const int b    = blockIdx.x / NT;

    const float* q0 = partBG + ((size_t)(b * 2 * NT + tile * 2)) * (2 * TPX);
    const float* q1 = q0 + 2 * TPX;

    float ssT = q0[tid] + q1[tid];
    float dgT = q0[TPX + tid] + q1[TPX + tid];
    float pbg = dgT * (1.0f / fmaxf(sqrtf(ssT), 1e-10f));

    float pv[VO];
    pv[0] = pbg;
    const float* pc = probC + (size_t)b * VV * HWSZ + tile * TPX + tid;
    #pragma unroll
    for (int v = 0; v < VV; ++v) pv[v + 1] = pc[(size_t)v * HWSZ];

    float m = pv[0];
    #pragma unroll
    for (int i = 1; i < VO; ++i) m = fmaxf(m, pv[i]);
    float se = 0.f;
    #pragma unroll
    for (int i = 0; i < VO; ++i) { pv[i] = __expf(pv[i] - m); se += pv[i]; }
    float inv = 1.0f / se;

    float* dstp = out + (size_t)b * VO * HWSZ + tile * TPX + tid;
    #pragma unroll
    for (int i = 0; i < VO; ++i) dstp[(size_t)i * HWSZ] = pv[i] * inv;
}

extern "C" void kernel_launch(void* const* d_in, const int* in_sizes, int n_in,
                              void* d_out, int out_size, void* d_ws, size_t ws_size,
                              hipStream_t stream) {
    const float* codeC  = (const float*)d_in[0];
    const float* codeBG = (const float*)d_in[1];
    const float* refc   = (const float*)d_in[2];
    // d_in[3] (ref_code_bg) unused by the reference
    const int* coord = (const int*)d_in[4];
    const int* cls   = (const int*)d_in[5];
    float* out = (float*)d_out;

    char* ws = (char*)d_ws;
    float*    protosT  = (float*)   (ws);              // 40,960 B  [c][v]
    float*    probC    = (float*)   (ws + 40960);      // 4,096,000 B
    float*    minvecN  = (float*)   (ws + 4136960);    // 16,384 B
    u64*      batchMin = (u64*)     (ws + 4153344);    // 64 B
    unsigned* batchCnt = (unsigned*)(ws + 4153408);    // 32 B
    float*    partC    = (float*)   (ws + 4153472);    // 400*21*256*4 = 8,601,600 B
    float*    partBG   = (float*)   (ws + 12755072);   // 400*2*256*4 = 819,200 B

    k_protos    <<<dim3(VV),          dim3(512), 0, stream>>>(refc, coord, cls, protosT,
                                                              batchMin, batchCnt);
    k_probC_part<<<dim3(BB * NT * 2), dim3(256), 0, stream>>>(codeC, protosT, partC);
    k_finishC   <<<dim3(BB * NT),     dim3(256), 0, stream>>>(partC, codeBG, probC,
                                                              batchMin, batchCnt, minvecN);
    k_bg_part   <<<dim3(BB * NT * 2), dim3(256), 0, stream>>>(codeBG, minvecN, partBG);
    k_finishBG  <<<dim3(BB * NT),     dim3(256), 0, stream>>>(partBG, probC, out);
}

// Round 9
// 70.009 us; speedup vs baseline: 3.1114x; 1.6673x over previous
//
#include <hip/hip_runtime.h>
#include <math.h>

#define BB 8
#define CC 512
#define HWSZ 6400
#define NN 100
#define HR 40
#define WR 40
#define VV 20        // N_CLASSES_FG
#define VO 21        // BG + FG
#define TPX 256      // pixels per tile
#define NT (HWSZ / TPX)      // 25 tiles

typedef unsigned long long u64;
typedef float f4 __attribute__((ext_vector_type(4)));

// order-preserving float -> uint32 map (min float == min uint)
__device__ __forceinline__ unsigned mapf(float f) {
    unsigned b = __float_as_uint(f);
    return (b & 0x80000000u) ? ~b : (b | 0x80000000u);
}

// ---------------- K1: normalized prototypes, transposed [c][v]; init batchMin
__global__ __launch_bounds__(512) void k_protos(const float* __restrict__ refc,
                                                const int* __restrict__ coord,
                                                const int* __restrict__ cls,
                                                float* __restrict__ protosT,
                                                u64* __restrict__ batchMin) {
    const int v = blockIdx.x;        // class
    const int c = threadIdx.x;       // channel
    if (v == 0 && c < BB) batchMin[c] = ~0ull;

    float acc = 0.f;
    int cnt = 0;
    for (int n = 0; n < NN; ++n) {
        if (cls[n] == v) {           // uniform across block
            int y = coord[2 * n + 1];
            int x = coord[2 * n + 0];
            acc += refc[((size_t)(n * CC + c) * HR + y) * WR + x];
            ++cnt;
        }
    }
    acc /= fmaxf((float)cnt, 1.0f);

    float ss = acc * acc;
    #pragma unroll
    for (int off = 32; off; off >>= 1) ss += __shfl_xor(ss, off);
    __shared__ float sW[8];
    const int wave = c >> 6, lane = c & 63;
    if (lane == 0) sW[wave] = ss;
    __syncthreads();
    float tot = 0.f;
    #pragma unroll
    for (int w = 0; w < 8; ++w) tot += sW[w];
    float scale = 1.0f / fmaxf(sqrtf(tot), 1e-10f);

    protosT[c * VV + v] = acc * scale;
}

// ---------------- K2: partial prob_C sums, float4 NT streaming --------------
// grid = 8b x 25tiles x 2 channel-halves = 400; block = 256 = 4 waves.
// wave w owns channels [cg*256 + w*64, +64); lane owns float4 @ px 4*lane.
// Writes RAW partial sums partC[blk][21][256]  (row0 = ss, rows 1..20 = d).
__global__ __launch_bounds__(256) void k_probC_part(const float* __restrict__ codeC,
                                                    const float* __restrict__ protosT,
                                                    float* __restrict__ partC) {
    __shared__ float red[4 * 11 * TPX];   // 45 KB

    const int tid  = threadIdx.x;
    const int w    = tid >> 6, lane = tid & 63;
    const int blk  = blockIdx.x;          // b*50 + tile*2 + cg
    const int cg   = blk & 1;
    const int tile = (blk >> 1) % NT;
    const int b    = blk / (2 * NT);
    const int c0   = __builtin_amdgcn_readfirstlane(cg * 256 + w * 64);

    const float* src = codeC + ((size_t)(b * CC + c0)) * HWSZ + tile * TPX + 4 * lane;
    const float* pt  = protosT + (size_t)c0 * VV;   // wave-uniform -> s_load

    f4 d[VV];
    #pragma unroll
    for (int v = 0; v < VV; ++v) d[v] = (f4)(0.f);
    f4 ss = (f4)(0.f);

    #pragma unroll 8
    for (int c = 0; c < 64; ++c) {
        f4 x = __builtin_nontemporal_load((const f4*)(src + (size_t)c * HWSZ));
        ss.x = fmaf(x.x, x.x, ss.x);
        ss.y = fmaf(x.y, x.y, ss.y);
        ss.z = fmaf(x.z, x.z, ss.z);
        ss.w = fmaf(x.w, x.w, ss.w);
        const float* pr = pt + c * VV;
        #pragma unroll
        for (int v = 0; v < VV; ++v) {
            float p = pr[v];
            d[v].x = fmaf(x.x, p, d[v].x);
            d[v].y = fmaf(x.y, p, d[v].y);
            d[v].z = fmaf(x.z, p, d[v].z);
            d[v].w = fmaf(x.w, p, d[v].w);
        }
    }

    float* dstp = partC + (size_t)blk * (VO * TPX);

    // round A: ss + d0..d9 -> part rows 0..10
    *(f4*)&red[(w * 11 + 0) * TPX + 4 * lane] = ss;
    #pragma unroll
    for (int r = 0; r < 10; ++r)
        *(f4*)&red[(w * 11 + 1 + r) * TPX + 4 * lane] = d[r];
    __syncthreads();
    for (int q = tid; q < 11 * TPX; q += 256) {
        float t = red[q] + red[11 * TPX + q] + red[22 * TPX + q] + red[33 * TPX + q];
        dstp[q] = t;
    }
    __syncthreads();

    // round B: d10..d19 -> part rows 11..20
    #pragma unroll
    for (int r = 0; r < 10; ++r)
        *(f4*)&red[(w * 11 + r) * TPX + 4 * lane] = d[10 + r];
    __syncthreads();
    for (int q = tid; q < 10 * TPX; q += 256) {
        float t = red[q] + red[11 * TPX + q] + red[22 * TPX + q] + red[33 * TPX + q];
        dstp[11 * TPX + q] = t;
    }
}

// ---------------- K2b: combine halves -> probC + psum + argmin --------------
// grid = 8b x 25tiles = 200; block = 256 (thread = pixel).
__global__ __launch_bounds__(256) void k_finishC(const float* __restrict__ partC,
                                                 float* __restrict__ probC,
                                                 u64* __restrict__ batchMin) {
    __shared__ u64 sKey[4];
    const int tid  = threadIdx.x;               // px
    const int tile = blockIdx.x % NT;
    const int b    = blockIdx.x / NT;

    const float* p0 = partC + ((size_t)(b * 2 * NT + tile * 2)) * (VO * TPX);
    const float* p1 = p0 + VO * TPX;

    float ssT = p0[tid] + p1[tid];
    float scale = 1.0f / fmaxf(sqrtf(ssT), 1e-10f);

    float psum = 0.f;
    float* dst = probC + (size_t)b * VV * HWSZ + tile * TPX;
    #pragma unroll
    for (int v = 0; v < VV; ++v) {
        float dv = p0[(1 + v) * TPX + tid] + p1[(1 + v) * TPX + tid];
        float pv = dv * scale;
        dst[(size_t)v * HWSZ + tid] = pv;
        psum += pv;
    }

    u64 key = ((u64)mapf(psum) << 32) | (unsigned)(tile * TPX + tid);
    #pragma unroll
    for (int off = 32; off; off >>= 1) {
        u64 o = __shfl_xor(key, off);
        if (o < key) key = o;
    }
    if ((tid & 63) == 0) sKey[tid >> 6] = key;
    __syncthreads();
    if (tid == 0) {
        u64 kk = sKey[0];
        kk = sKey[1] < kk ? sKey[1] : kk;
        kk = sKey[2] < kk ? sKey[2] : kk;
        kk = sKey[3] < kk ? sKey[3] : kk;
        atomicMin(&batchMin[b], kk);
    }
}

// ---------------- K3: normalize code_BG at the argmin pixel -----------------
__global__ __launch_bounds__(512) void k_minvec(const u64* __restrict__ batchMin,
                                                const float* __restrict__ codeBG,
                                                float* __restrict__ minvecN) {
    const int b = blockIdx.x, c = threadIdx.x;
    const int pix = (int)(unsigned)(batchMin[b] & 0xFFFFFFFFull);
    float x = codeBG[(size_t)(b * CC + c) * HWSZ + pix];
    float ss = x * x;
    #pragma unroll
    for (int off = 32; off; off >>= 1) ss += __shfl_xor(ss, off);
    __shared__ float sW[8];
    if ((c & 63) == 0) sW[c >> 6] = ss;
    __syncthreads();
    float tot = 0.f;
    #pragma unroll
    for (int w = 0; w < 8; ++w) tot += sW[w];
    minvecN[b * CC + c] = x * (1.0f / fmaxf(sqrtf(tot), 1e-10f));
}

// ---------------- K4: partial prob_BG sums, float4 NT streaming -------------
// Same decomposition as K2. Writes partBG[blk][2][256]  (ss row, dg row).
__global__ __launch_bounds__(256) void k_bg_part(const float* __restrict__ codeBG,
                                                 const float* __restrict__ minvecN,
                                                 float* __restrict__ partBG) {
    __shared__ float red[4 * 2 * TPX];   // 8 KB

    const int tid  = threadIdx.x;
    const int w    = tid >> 6, lane = tid & 63;
    const int blk  = blockIdx.x;
    const int cg   = blk & 1;
    const int tile = (blk >> 1) % NT;
    const int b    = blk / (2 * NT);
    const int c0   = __builtin_amdgcn_readfirstlane(cg * 256 + w * 64);

    const float* src = codeBG + ((size_t)(b * CC + c0)) * HWSZ + tile * TPX + 4 * lane;
    const float* mv  = minvecN + b * CC + c0;   // wave-uniform -> s_load

    f4 ss = (f4)(0.f);
    f4 dg = (f4)(0.f);

    #pragma unroll 8
    for (int c = 0; c < 64; ++c) {
        f4 x = __builtin_nontemporal_load((const f4*)(src + (size_t)c * HWSZ));
        float m = mv[c];
        ss.x = fmaf(x.x, x.x, ss.x);
        ss.y = fmaf(x.y, x.y, ss.y);
        ss.z = fmaf(x.z, x.z, ss.z);
        ss.w = fmaf(x.w, x.w, ss.w);
        dg.x = fmaf(x.x, m, dg.x);
        dg.y = fmaf(x.y, m, dg.y);
        dg.z = fmaf(x.z, m, dg.z);
        dg.w = fmaf(x.w, m, dg.w);
    }

    *(f4*)&red[(w * 2 + 0) * TPX + 4 * lane] = ss;
    *(f4*)&red[(w * 2 + 1) * TPX + 4 * lane] = dg;
    __syncthreads();

    float* dstp = partBG + (size_t)blk * (2 * TPX);
    for (int q = tid; q < 2 * TPX; q += 256) {
        float t = red[q] + red[2 * TPX + q] + red[4 * TPX + q] + red[6 * TPX + q];
        dstp[q] = t;
    }
}

// ---------------- K4b: combine halves -> prob_BG + softmax + out ------------
__global__ __launch_bounds__(256) void k_finishBG(const float* __restrict__ partBG,
                                                  const float* __restrict__ probC,
                                                  float* __restrict__ out) {
    const int tid  = threadIdx.x;               // px
    const int tile = blockIdx.x % NT;
    const int b    = blockIdx.x / NT;

    const float* q0 = partBG + ((size_t)(b * 2 * NT + tile * 2)) * (2 * TPX);
    const float* q1 = q0 + 2 * TPX;

    float ssT = q0[tid] + q1[tid];
    float dgT = q0[TPX + tid] + q1[TPX + tid];
    float pbg = dgT * (1.0f / fmaxf(sqrtf(ssT), 1e-10f));

    float pv[VO];
    pv[0] = pbg;
    const float* pc = probC + (size_t)b * VV * HWSZ + tile * TPX + tid;
    #pragma unroll
    for (int v = 0; v < VV; ++v) pv[v + 1] = pc[(size_t)v * HWSZ];

    float m = pv[0];
    #pragma unroll
    for (int i = 1; i < VO; ++i) m = fmaxf(m, pv[i]);
    float se = 0.f;
    #pragma unroll
    for (int i = 0; i < VO; ++i) { pv[i] = __expf(pv[i] - m); se += pv[i]; }
    float inv = 1.0f / se;

    float* dstp = out + (size_t)b * VO * HWSZ + tile * TPX + tid;
    #pragma unroll
    for (int i = 0; i < VO; ++i) dstp[(size_t)i * HWSZ] = pv[i] * inv;
}

extern "C" void kernel_launch(void* const* d_in, const int* in_sizes, int n_in,
                              void* d_out, int out_size, void* d_ws, size_t ws_size,
                              hipStream_t stream) {
    const float* codeC  = (const float*)d_in[0];
    const float* codeBG = (const float*)d_in[1];
    const float* refc   = (const float*)d_in[2];
    // d_in[3] (ref_code_bg) unused by the reference
    const int* coord = (const int*)d_in[4];
    const int* cls   = (const int*)d_in[5];
    float* out = (float*)d_out;

    char* ws = (char*)d_ws;
    float* protosT  = (float*)(ws);                    // 40,960 B  [c][v]
    float* probC    = (float*)(ws + 40960);            // 4,096,000 B
    float* minvecN  = (float*)(ws + 4136960);          // 16,384 B
    u64*   batchMin = (u64*)  (ws + 4153344);          // 64 B
    float* partC    = (float*)(ws + 4153408);          // 400*21*256*4 = 8,601,600 B
    float* partBG   = (float*)(ws + 12755008);         // 400*2*256*4 = 819,200 B

    k_protos    <<<dim3(VV),          dim3(512), 0, stream>>>(refc, coord, cls, protosT, batchMin);
    k_probC_part<<<dim3(BB * NT * 2), dim3(256), 0, stream>>>(codeC, protosT, partC);
    k_finishC   <<<dim3(BB * NT),     dim3(256), 0, stream>>>(partC, probC, batchMin);
    k_minvec    <<<dim3(BB),          dim3(512), 0, stream>>>(batchMin, codeBG, minvecN);
    k_bg_part   <<<dim3(BB * NT * 2), dim3(256), 0, stream>>>(codeBG, minvecN, partBG);
    k_finishBG  <<<dim3(BB * NT),     dim3(256), 0, stream>>>(partBG, probC, out);
}